// Round 3
// baseline (137.139 us; speedup 1.0000x reference)
//
#include <hip/hip_runtime.h>

// YOLO-v1 style loss, fused single pass.
// pred: (8192,7,7,30) f32, gt: (8192,7,7,30) f32 -> scalar f32 (= total/8192).
//
// R2 post-mortem: per-cell direct loads are scatter-bound at the TA (64 lanes
// x distinct lines per VMEM instr). R3: coalesced global->LDS DMA via
// __builtin_amdgcn_global_load_lds (width 16, linear LDS = flat tile copy,
// no dest VGPRs -> whole 30KB tile in flight per block), then per-cell
// float2 reads from LDS (stride-30 words, 4-way conflict, minor).
// 128 cells/block * 120 B = 15 chunks of 1024 B per tensor.

#define NCH 30
#define TPB 128           // threads = cells per block
#define CHUNKS 15         // TPB*NCH*4 / 1024
#define INV_B (1.0f / 8192.0f)

typedef __attribute__((address_space(1))) void gvoid_t;
typedef __attribute__((address_space(3))) void lvoid_t;

__device__ __forceinline__ void gload16(const void* g, void* l) {
    __builtin_amdgcn_global_load_lds((gvoid_t*)g, (lvoid_t*)l, 16, 0, 0);
}

__global__ __launch_bounds__(TPB)
void yolo_loss_kernel(const float* __restrict__ pred,
                      const float* __restrict__ gt,
                      float* __restrict__ out,
                      int ncells)
{
    __shared__ float sp[TPB * NCH];   // 15360 B, linear copy of pred tile
    __shared__ float sg[TPB * NCH];   // 15360 B, linear copy of gt tile
    __shared__ float wsum[TPB / 64];

    const int tid  = threadIdx.x;
    const int lane = tid & 63;
    const int wave = tid >> 6;

    const long long baseFloat = (long long)blockIdx.x * TPB * NCH;
    const long long totalBytes = (long long)ncells * NCH * 4;

    const char* gp = (const char*)(pred + baseFloat);
    const char* gg = (const char*)(gt   + baseFloat);
    char* lp = (char*)sp;
    char* lg = (char*)sg;

    // ---- stage: 15 x 1024B chunks per tensor, split across the 2 waves.
    // LDS dest = wave-uniform base + lane*16 (linear); global src per-lane.
    for (int i = wave; i < CHUNKS; i += 2) {
        const int off = i * 1024 + lane * 16;
        if (baseFloat * 4 + off + 16 <= totalBytes) {
            gload16(gp + off, lp + off);
            gload16(gg + off, lg + off);
        }
    }
    __syncthreads();   // compiler emits s_waitcnt vmcnt(0) before barrier

    // ---- per-cell loss (verified math from R1/R2, absmax == 0)
    float cell_loss = 0.0f;
    const long long cell = baseFloat / NCH + tid;
    if (cell < ncells) {
        const float2* cp = (const float2*)(sp + tid * NCH);
        const float2* cg = (const float2*)(sg + tid * NCH);

        float2 p[15];
#pragma unroll
        for (int j = 0; j < 15; ++j) p[j] = cp[j];

        const float2 g0 = cg[0];
        const float2 g1 = cg[1];
        const float2 g2 = cg[2];          // .x = obj flag
        float2 gcl[10];
#pragma unroll
        for (int j = 0; j < 10; ++j) gcl[j] = cg[5 + j];

        const float gx = g0.x, gy = g0.y, gw = g1.x, gh = g1.y;
        const float gc = g2.x;
        const float obj   = (gc > 0.0f) ? 1.0f : 0.0f;
        const float noobj = (gc == 0.0f) ? 1.0f : 0.0f;

        const float ghw = 3.5f * gw, ghh = 3.5f * gh;   // 0.5*GRID*wh
        const float a2 = 49.0f * gw * gh;

        const float px[2] = {p[0].x, p[2].y};
        const float py[2] = {p[0].y, p[3].x};
        const float pw[2] = {p[1].x, p[3].y};
        const float ph[2] = {p[1].y, p[4].x};
        const float pc[2] = {p[2].x, p[4].y};

        float iou[2];
#pragma unroll
        for (int k = 0; k < 2; ++k) {
            const float phw = 3.5f * pw[k], phh = 3.5f * ph[k];
            const float ltx = fmaxf(px[k] - phw, gx - ghw);
            const float rbx = fminf(px[k] + phw, gx + ghw);
            const float lty = fmaxf(py[k] - phh, gy - ghh);
            const float rby = fminf(py[k] + phh, gy + ghh);
            const float w = fmaxf(rbx - ltx, 0.0f);
            const float h = fmaxf(rby - lty, 0.0f);
            const float inter = w * h;
            const float a1 = 49.0f * pw[k] * ph[k];
            iou[k] = inter / (a1 + a2 - inter);
        }

        // argmax first-max tie-break: box1 wins only if strictly greater
        const int r = (iou[1] > iou[0]) ? 1 : 0;
        const float max_iou = fmaxf(iou[0], iou[1]);

        const float dx = px[r] - gx;
        const float dy = py[r] - gy;
        const float dw = sqrtf(pw[r]) - sqrtf(gw);
        const float dh = sqrtf(ph[r]) - sqrtf(gh);
        const float coord = dx * dx + dy * dy + dw * dw + dh * dh;

        const float d = pc[r] - max_iou;
        const float resp_l = d * d;
        const float irr_l = pc[1 - r] * pc[1 - r];

        const float d0 = pc[0] - gc, d1 = pc[1] - gc;
        const float noobj_l = d0 * d0 + d1 * d1;

        float cls = 0.0f;
#pragma unroll
        for (int j = 0; j < 10; ++j) {
            const float ex = p[5 + j].x - gcl[j].x;
            const float ey = p[5 + j].y - gcl[j].y;
            cls += ex * ex + ey * ey;
        }

        // total = 5*coord + 2*resp + 0.5*noobj + cls + irr (resp counted twice)
        cell_loss = obj * (5.0f * coord + 2.0f * resp_l + irr_l + cls)
                  + noobj * 0.5f * noobj_l;
    }

    // ---- reduce: wave64 shuffle -> block -> one atomic
    float v = cell_loss * INV_B;
#pragma unroll
    for (int off = 32; off > 0; off >>= 1)
        v += __shfl_down(v, off, 64);
    if ((tid & 63) == 0) wsum[tid >> 6] = v;
    __syncthreads();
    if (tid == 0) {
        float s = 0.0f;
#pragma unroll
        for (int w = 0; w < TPB / 64; ++w) s += wsum[w];
        atomicAdd(out, s);
    }
}

extern "C" void kernel_launch(void* const* d_in, const int* in_sizes, int n_in,
                              void* d_out, int out_size, void* d_ws, size_t ws_size,
                              hipStream_t stream)
{
    const float* pred = (const float*)d_in[0];
    const float* gt   = (const float*)d_in[1];
    float* out = (float*)d_out;

    const int ncells = in_sizes[0] / NCH;           // 8192*49 = 401408
    const int nblocks = (ncells + TPB - 1) / TPB;   // 3136 (exact)

    hipMemsetAsync(out, 0, sizeof(float), stream);
    yolo_loss_kernel<<<nblocks, TPB, 0, stream>>>(pred, gt, out, ncells);
}

// Round 4
// 116.669 us; speedup vs baseline: 1.1755x; 1.1755x over previous
//
#include <hip/hip_runtime.h>

// YOLO-v1 style loss, fused single pass + separate final reduce.
// pred: (8192,7,7,30) f32, gt: (8192,7,7,30) f32 -> scalar f32 (= total/8192).
//
// R3 post-mortem: all three load structures (LDS transpose, direct loads,
// global_load_lds DMA) floor at 39-52 us. Shared component: 1568-3136
// device-scope same-address atomicAdds -- serialized cross-XCD, blocks can't
// retire until their atomic completes. R4: identical to R2 (fastest base)
// except blocks store partials to d_ws (unique addresses, no atomics); a
// second 1-block kernel reduces 1568 partials and writes out[0] (no memset
// dispatch needed).

#define NCH 30
#define TPB 256
#define INV_B (1.0f / 8192.0f)

__global__ __launch_bounds__(TPB)
void yolo_main(const float* __restrict__ pred,
               const float* __restrict__ gt,
               float* __restrict__ partial,
               int ncells)
{
    __shared__ float wsum[TPB / 64];

    const int tid = threadIdx.x;
    const int cell = blockIdx.x * TPB + tid;

    float cell_loss = 0.0f;
    if (cell < ncells) {
        const float* cp = pred + (long long)cell * NCH;
        const float* cg = gt + (long long)cell * NCH;

        // ---- load pred: all 30 channels as 15 float2 (independent loads)
        float2 p[15];
#pragma unroll
        for (int j = 0; j < 15; ++j)
            p[j] = *(const float2*)(cp + 2 * j);

        // ---- load gt: box (ch 0..5) + classes (ch 10..29); skip dup box
        float2 g0 = *(const float2*)(cg + 0);
        float2 g1 = *(const float2*)(cg + 2);
        float2 g2 = *(const float2*)(cg + 4);   // .x = obj flag
        float2 gcl[10];
#pragma unroll
        for (int j = 0; j < 10; ++j)
            gcl[j] = *(const float2*)(cg + 10 + 2 * j);

        const float gx = g0.x, gy = g0.y, gw = g1.x, gh = g1.y;
        const float gc = g2.x;
        const float obj   = (gc > 0.0f) ? 1.0f : 0.0f;
        const float noobj = (gc == 0.0f) ? 1.0f : 0.0f;

        const float ghw = 3.5f * gw, ghh = 3.5f * gh;   // 0.5*GRID*wh
        const float a2 = 49.0f * gw * gh;

        const float px[2] = {p[0].x, p[2].y};
        const float py[2] = {p[0].y, p[3].x};
        const float pw[2] = {p[1].x, p[3].y};
        const float ph[2] = {p[1].y, p[4].x};
        const float pc[2] = {p[2].x, p[4].y};

        float iou[2];
#pragma unroll
        for (int k = 0; k < 2; ++k) {
            const float phw = 3.5f * pw[k], phh = 3.5f * ph[k];
            const float ltx = fmaxf(px[k] - phw, gx - ghw);
            const float rbx = fminf(px[k] + phw, gx + ghw);
            const float lty = fmaxf(py[k] - phh, gy - ghh);
            const float rby = fminf(py[k] + phh, gy + ghh);
            const float w = fmaxf(rbx - ltx, 0.0f);
            const float h = fmaxf(rby - lty, 0.0f);
            const float inter = w * h;
            const float a1 = 49.0f * pw[k] * ph[k];
            iou[k] = inter / (a1 + a2 - inter);
        }

        // argmax first-max tie-break: box1 wins only if strictly greater
        const int r = (iou[1] > iou[0]) ? 1 : 0;
        const float max_iou = fmaxf(iou[0], iou[1]);

        const float dx = px[r] - gx;
        const float dy = py[r] - gy;
        const float dw = sqrtf(pw[r]) - sqrtf(gw);
        const float dh = sqrtf(ph[r]) - sqrtf(gh);
        const float coord = dx * dx + dy * dy + dw * dw + dh * dh;

        const float d = pc[r] - max_iou;
        const float resp_l = d * d;
        const float irr_l = pc[1 - r] * pc[1 - r];

        const float d0 = pc[0] - gc, d1 = pc[1] - gc;
        const float noobj_l = d0 * d0 + d1 * d1;

        float cls = 0.0f;
#pragma unroll
        for (int j = 0; j < 10; ++j) {
            const float ex = p[5 + j].x - gcl[j].x;
            const float ey = p[5 + j].y - gcl[j].y;
            cls += ex * ex + ey * ey;
        }

        // total = 5*coord + 2*resp + 0.5*noobj + cls + irr (resp counted 2x)
        cell_loss = obj * (5.0f * coord + 2.0f * resp_l + irr_l + cls)
                  + noobj * 0.5f * noobj_l;
    }

    // ---- reduce: wave64 shuffle -> block -> one plain store (NO atomic)
    float v = cell_loss;
#pragma unroll
    for (int off = 32; off > 0; off >>= 1)
        v += __shfl_down(v, off, 64);
    if ((tid & 63) == 0) wsum[tid >> 6] = v;
    __syncthreads();
    if (tid == 0) {
        float s = 0.0f;
#pragma unroll
        for (int w = 0; w < TPB / 64; ++w) s += wsum[w];
        partial[blockIdx.x] = s;
    }
}

__global__ __launch_bounds__(256)
void yolo_reduce(const float* __restrict__ partial,
                 float* __restrict__ out,
                 int n)
{
    __shared__ float wsum[4];
    const int tid = threadIdx.x;

    float s = 0.0f;
    for (int i = tid; i < n; i += 256)
        s += partial[i];

#pragma unroll
    for (int off = 32; off > 0; off >>= 1)
        s += __shfl_down(s, off, 64);
    if ((tid & 63) == 0) wsum[tid >> 6] = s;
    __syncthreads();
    if (tid == 0) {
        float t = wsum[0] + wsum[1] + wsum[2] + wsum[3];
        out[0] = t * INV_B;
    }
}

extern "C" void kernel_launch(void* const* d_in, const int* in_sizes, int n_in,
                              void* d_out, int out_size, void* d_ws, size_t ws_size,
                              hipStream_t stream)
{
    const float* pred = (const float*)d_in[0];
    const float* gt   = (const float*)d_in[1];
    float* out = (float*)d_out;
    float* partial = (float*)d_ws;

    const int ncells = in_sizes[0] / NCH;           // 8192*49 = 401408
    const int nblocks = (ncells + TPB - 1) / TPB;   // 1568 (exact)

    yolo_main<<<nblocks, TPB, 0, stream>>>(pred, gt, partial, ncells);
    yolo_reduce<<<1, 256, 0, stream>>>(partial, out, nblocks);
}